// Round 5
// baseline (1063.902 us; speedup 1.0000x reference)
//
#include <hip/hip_runtime.h>
#include <hip/hip_bf16.h>

// LSNN forward: encoder(IF, soft reset) -> hidden(LIF alpha=0.9) -> leaky integrator out.
// Pipeline:
//   k_enc       : x -> s_e spike bitmasks [B][T][4]u64           (bit-exact vs ref)
//   k_quant     : W_hdn -> dual-plane bf16 W'^T [n=1024][k=512]  (hi + residual)
//   k_quant_o   : W_otp -> dual-plane bf16 [n=16 pad][k=2048]
//   k_gemm_scan : ONE launch; each block loops all 16 Tc=64 chunks, S_e @ [Whi;Wlo]
//                 via MFMA, hidden-LIF scan fused in epilogue, carry in registers.
//   k_outcur_mfma: s_h masks @ W_otp via MFMA -> I[b][t][c]
//   k_integ1/2/3: chunked parallel beta-scan of I -> d_out
//
// R4: [n][t] epilogue scratch (b128), DMA B-staging w/ source-side swizzle,
//     conflicts -> 0. Left at MfmaUtil 37% + VALUBusy 54% (= serialized pipes).
// R5 (arithmetic bit-identical; R5a fixes compile: writelane -> cndmask collect):
//   - 2-kt rounds, two 32KB B buffers: 6 barriers/chunk (was 10).
//   - all LDS addressing hoisted to persistent VGPRs + offset immediates
//     (Mld moved to LDS base so kt/mg fold into imm; B reads vaddr bb[kw] +
//     imm 32768*rd + 16384*s + 2048*ng; epilogue XOR fields separable).
//   - s_setprio(1) around MFMA clusters (2 un-synced blocks/CU -> arbitration).
//   - mh layout [word][m]: coalesced gemm stores + contiguous outcur reads.

#define BB 512
#define TT 1024
#define OO 128
#define KK 256
#define HH 1024
#define CC 10
#define TC 64
#define NCHUNK (TT / TC)
#define MTOT ((size_t)BB * TT)

typedef unsigned long long u64;
typedef __attribute__((ext_vector_type(8))) short short8;   // 8 x bf16
typedef __attribute__((ext_vector_type(4))) float floatx4;
typedef __attribute__((ext_vector_type(4))) int intx4;

__device__ __forceinline__ unsigned short f2bf_rn(float f) {
    unsigned u = __float_as_uint(f);
    u += 0x7FFFu + ((u >> 16) & 1u);      // round-to-nearest-even (finite inputs)
    return (unsigned short)(u >> 16);
}
__device__ __forceinline__ float bf2f(unsigned short h) {
    return __uint_as_float(((unsigned)h) << 16);
}

// 8 bits -> 8 x bf16 {0.0, 1.0}, element j = bit j.
__device__ __forceinline__ short8 bitsx8_bf16(unsigned e) {
    union { short8 s; unsigned u[4]; } r;
#pragma unroll
    for (int j = 0; j < 4; ++j) {
        unsigned t = (e >> (2 * j)) & 3u;
        r.u[j] = (((t << 15) | t) & 0x10001u) * 0x3F80u;
    }
    return r.s;
}

// async 4KB wave stage of one 16KB kt-subtile's wave-share:
// LDS[row][piece] = Wt_row[piece ^ (row&7)] via per-lane global src
// (lane covers row=base+(lane>>3), srcpiece=(lane&7)^(lane>>3)),
// LDS dest = wave-uniform base + lane*16 (linear).
__device__ __forceinline__ void stage_kt(char* dstbuf /*wave-uniform*/,
                                         const unsigned short* gsrc /*per-lane*/,
                                         int kt) {
#pragma unroll
    for (int i = 0; i < 4; ++i) {
        const unsigned short* g = gsrc + (size_t)i * 8 * 512 + kt * 64;
        char* l = dstbuf + i * 1024;
        __builtin_amdgcn_global_load_lds(
            (const __attribute__((address_space(1))) unsigned int*)g,
            (__attribute__((address_space(3))) unsigned int*)l, 16, 0, 0);
    }
}

// ---------------------------------------------------------------- encoder ----
__global__ __launch_bounds__(128) void k_enc(const float* __restrict__ x,
                                             u64* __restrict__ me) {
    const int b    = blockIdx.x;
    const int j    = threadIdx.x;       // channel 0..127
    const int wv   = j >> 6;            // wave 0/1
    const int lane = j & 63;
    const float* xb = x + (size_t)b * (TT * OO);
    float vp = 0.f, vn = 0.f;
    for (int t0 = 0; t0 < TT; t0 += 16) {
        float xs[16];
#pragma unroll
        for (int g = 0; g < 16; ++g) xs[g] = xb[(t0 + g) * OO + j];  // independent loads
#pragma unroll
        for (int g = 0; g < 16; ++g) {
            float xv = xs[g];
            float cp = fmaxf(xv, 0.f);
            float cn = fmaxf(-xv, 0.f);
            vp += cp;                    // same per-channel op order as ref -> bit-exact
            vn += cn;
            bool sp = (vp >= 1.0f);
            bool sn = (vn >= 1.0f);
            u64 mp = __ballot(sp);
            u64 mn = __ballot(sn);
            if (sp) vp -= 1.0f;
            if (sn) vn -= 1.0f;
            if (lane == 0) {
                size_t r = ((size_t)b * TT + (t0 + g)) * 4;
                me[r + wv]     = mp;
                me[r + 2 + wv] = mn;
            }
        }
    }
}

// ---------------------------------------------------- W_hdn dual-plane bf16 --
__global__ __launch_bounds__(256) void k_quant(const float* __restrict__ Wh,
                                               unsigned short* __restrict__ Wt) {
    int idx = blockIdx.x * 256 + threadIdx.x;   // 1024*512 total
    int n = idx >> 9;
    int k = idx & 511;
    float w = Wh[(size_t)(k & 255) * HH + n];
    unsigned short hi = f2bf_rn(w);
    unsigned short out = (k < KK) ? hi : f2bf_rn(w - bf2f(hi));
    Wt[(size_t)n * 512 + k] = out;
}

// ---------------------------------------------------- W_otp dual-plane bf16 --
__global__ __launch_bounds__(256) void k_quant_o(const float* __restrict__ Wo,
                                                 unsigned short* __restrict__ Wqo) {
    int idx = blockIdx.x * 256 + threadIdx.x;   // 16*2048 = 32768
    int n = idx >> 11;
    int k = idx & 2047;
    unsigned short out = 0;
    if (n < CC) {
        float w = Wo[(size_t)(k & 1023) * CC + n];
        unsigned short hi = f2bf_rn(w);
        out = (k < HH) ? hi : f2bf_rn(w - bf2f(hi));
    }
    Wqo[(size_t)n * 2048 + k] = out;
}

// ------------------------------------------- fused GEMM + hidden LIF scan ----
// ONE launch, grid (128 m-tiles, 8 n-slices), 256 threads. Block tile 256m x 128n,
// K=512. Each block loops ct = 0..15 chunks; wave w owns batch mtile*4+w, all 64 t
// of the chunk, 128 n. LIF carry in 2 VGPRs per lane across the whole T=1024 scan.
// LDS: [0,8K) Mld [4 words][256 rows]; [8K,40K) bufA (2 kt x 16KB); [40K,72K) bufB.
// Epilogue scr (16KB/wave) aliases [8K,72K).
__global__ __launch_bounds__(256, 2) void k_gemm_scan(
    const u64* __restrict__ me, const unsigned short* __restrict__ Wt,
    u64* __restrict__ mh) {
    __shared__ __align__(16) char smem[73728];
    u64* Mld = (u64*)smem;                  // [4 words][256 rows]

    const int tid  = threadIdx.x;
    const int wave = tid >> 6;
    const int lane = tid & 63;
    const int quad = lane >> 4;
    const int l15  = lane & 15;
    const int h2   = l15 >> 2;
    const int mtile = blockIdx.x;           // 0..127
    const int ny    = blockIdx.y;           // 0..7

    const int b = mtile * 4 + wave;         // this wave's batch row
    float vh0 = 0.f, vh1 = 0.f;             // LIF carry for n = ny*128 + h*64 + lane

    // per-lane pre-swizzled global source for DMA staging (constant over chunks/kt)
    const unsigned short* gsrc =
        Wt + (size_t)(ny * 128 + wave * 32 + (lane >> 3)) * 512 +
        (((lane & 7) ^ (lane >> 3)) * 8);
    char* dstA = smem + 8192 + wave * 4096;   // wave-uniform LDS DMA bases
    char* dstB = smem + 40960 + wave * 4096;

    // hoisted per-lane LDS byte offsets (all loop indices fold into offset imm)
    const int aoff = wave * 512 + l15 * 8;                        // Mld vaddr
    const int bb0 = 8192 + l15 * 128 + ((quad ^ (l15 & 7)) * 16);         // kw=0
    const int bb1 = 8192 + l15 * 128 + (((4 + quad) ^ (l15 & 7)) * 16);   // kw=1
    int sA[4], rA[4];
    {
        int sbase = 8192 + wave * 16384 + l15 * 256 + ((quad ^ (l15 & 3)) * 16);
#pragma unroll
        for (int mg = 0; mg < 4; ++mg) sA[mg] = sbase + ((mg ^ h2) * 64);
        int rbase = 8192 + wave * 16384 + lane * 256;
#pragma unroll
        for (int q4 = 0; q4 < 4; ++q4) rA[q4] = rbase + ((q4 ^ (l15 & 3)) * 16);
    }

    for (int ct = 0; ct < NCHUNK; ++ct) {
        const int t0 = ct * TC;

        __syncthreads();                    // all waves' prev-chunk scr reads done
        stage_kt(dstA, gsrc, 0);            // round 0: kt0, kt1 -> bufA
        stage_kt(dstA + 16384, gsrc, 1);
        { // stage masks transposed: Mld[w][row], row = tid (stride-8B: conflict-free)
            int m  = mtile * 256 + tid;
            int bb = m >> 6;
            int tl = m & 63;
            size_t base = ((size_t)bb * TT + (t0 + tl)) * 4;
#pragma unroll
            for (int w = 0; w < 4; ++w) Mld[w * 256 + tid] = me[base + w];
        }
        __syncthreads();                    // round0 DMA drained + Mld visible

        floatx4 acc[4][8];
#pragma unroll
        for (int i = 0; i < 4; ++i)
#pragma unroll
            for (int j2 = 0; j2 < 8; ++j2) acc[i][j2] = floatx4{0.f, 0.f, 0.f, 0.f};

#pragma unroll 2
        for (int rd = 0; rd < 4; ++rd) {    // 2 kt per round, 1 barrier per round
            if (rd < 3) {                   // issue next round's DMA first
                char* nxt = (rd & 1) ? dstA : dstB;
                stage_kt(nxt, gsrc, 2 * rd + 2);
                stage_kt(nxt + 16384, gsrc, 2 * rd + 3);
            }
            const int rofs = (rd & 1) ? 32768 : 0;
#pragma unroll
            for (int s = 0; s < 2; ++s) {
                const int kt = 2 * rd + s;
                u64 aw[4];
#pragma unroll
                for (int mg = 0; mg < 4; ++mg)   // imm-folded, conflict-free b64
                    aw[mg] = *(const u64*)(smem + aoff +
                                           ((kt & 3) * 2048 + mg * 128));
#pragma unroll
                for (int kw = 0; kw < 2; ++kw) {
                    const int shift = kw * 32 + quad * 8;
                    short8 afrag[4];
#pragma unroll
                    for (int mg = 0; mg < 4; ++mg)
                        afrag[mg] = bitsx8_bf16((unsigned)((aw[mg] >> shift) & 0xFFu));
                    const int bo = kw ? bb1 : bb0;
                    __builtin_amdgcn_s_setprio(1);
#pragma unroll
                    for (int ng = 0; ng < 8; ++ng) {
                        short8 bfrag = *(const short8*)(
                            smem + bo + (rofs + s * 16384 + ng * 2048));
#pragma unroll
                        for (int mg = 0; mg < 4; ++mg)
                            acc[mg][ng] = __builtin_amdgcn_mfma_f32_16x16x32_bf16(
                                afrag[mg], bfrag, acc[mg][ng], 0, 0, 0);
                    }
                    __builtin_amdgcn_s_setprio(0);
                }
            }
            __syncthreads();                 // reads of cur done; next buf published
        }

        // epilogue: per-wave LIF scan, scr layout [n_local][t], 16B-piece XOR swizzle.
        // C/D frag: n_local = ng2*16+l15, t = mg*16+quad*4+r -> one b128 per acc.
#pragma unroll
        for (int h = 0; h < 2; ++h) {
#pragma unroll
            for (int mg = 0; mg < 4; ++mg)
#pragma unroll
                for (int ng2 = 0; ng2 < 4; ++ng2)
                    *((floatx4*)(smem + sA[mg] + ng2 * 4096)) = acc[mg][h * 4 + ng2];
            // wave-private region: DS in-order per wave; compiler inserts lgkm wait.
            float v = h ? vh1 : vh0;
            u64 mym = 0;
#pragma unroll
            for (int g = 0; g < 4; ++g) {
                const int gofs = (g ^ h2) * 64;
                floatx4 cr[4];
#pragma unroll
                for (int q4 = 0; q4 < 4; ++q4)
                    cr[q4] = *((const floatx4*)(smem + (rA[q4] + gofs)));
#pragma unroll
                for (int q4 = 0; q4 < 4; ++q4)
#pragma unroll
                    for (int r = 0; r < 4; ++r) {
                        const int tl = g * 16 + q4 * 4 + r;
                        v = 0.9f * v + cr[q4][r];
                        bool sp = (v >= 1.0f);
                        u64 wm = __ballot(sp);
                        if (sp) v -= 1.0f;
                        if (lane == tl) mym = wm;   // cndmask-collect
                    }
            }
            // coalesced: word (ny*2+h), rows m = b*TT + t0 + lane (64 x 8B contig)
            mh[(size_t)(ny * 2 + h) * MTOT + (size_t)b * TT + t0 + lane] = mym;
            if (h) vh1 = v; else vh0 = v;
        }
    }
}

// ------------------------------------- s_h masks @ W_otp via MFMA -> I -------
// M = B*T = 524288 rows (m = b*1024 + t), N = 16 (10 used), K = 2048 (dual plane).
// mh layout [word wi][m]; word wi covers hidden units [64wi, 64wi+64).
__global__ __launch_bounds__(256, 2) void k_outcur_mfma(
    const u64* __restrict__ mh, const unsigned short* __restrict__ Wqo,
    float* __restrict__ I) {
    __shared__ __align__(16) char smem[65536];
    char* Bo = smem;                        // 64 KB: [n=16][k=2048] bf16, swizzled

    const int tid  = threadIdx.x;
    const int wave = tid >> 6;
    const int lane = tid & 63;
    const int quad = lane >> 4;
    const int l15  = lane & 15;

    { // stage Bo (16B pieces, XOR-swizzle low 3 piece bits by n)
#pragma unroll
        for (int i = 0; i < 16; ++i) {
            int pid = i * 256 + tid;        // 4096 pieces of 16 B
            int n = pid >> 8, p = pid & 255;
            intx4 v = ((const intx4*)Wqo)[pid];
            *((intx4*)(Bo + n * 4096 + ((p ^ (n & 7)) * 16))) = v;
        }
    }
    __syncthreads();

    const int tbase = blockIdx.x * 16 + wave * 4;   // 4 consecutive m-tiles per wave
    floatx4 acc[4];
#pragma unroll
    for (int tt = 0; tt < 4; ++tt) acc[tt] = floatx4{0.f, 0.f, 0.f, 0.f};

    for (int wi = 0; wi < 16; ++wi) {
        u64 w[4];
#pragma unroll
        for (int tt = 0; tt < 4; ++tt)      // 128B-contiguous per tt
            w[tt] = mh[(size_t)wi * MTOT + (size_t)(tbase + tt) * 16 + l15];
#pragma unroll
        for (int half = 0; half < 2; ++half) {
            int shift = half * 32 + quad * 8;
            int kt_hi = 2 * wi + half;           // hi-plane K chunk
            int kt_lo = 32 + kt_hi;              // lo-plane (residual) K chunk
            int j_hi = kt_hi * 4 + quad;
            int j_lo = kt_lo * 4 + quad;
            short8 bhi = *((const short8*)(Bo + l15 * 4096 + ((j_hi ^ (l15 & 7)) * 16)));
            short8 blo = *((const short8*)(Bo + l15 * 4096 + ((j_lo ^ (l15 & 7)) * 16)));
#pragma unroll
            for (int tt = 0; tt < 4; ++tt) {
                unsigned byte = (unsigned)((w[tt] >> shift) & 0xFFu);
                short8 af = bitsx8_bf16(byte);   // arithmetic A-frag (no LDS LUT)
                acc[tt] = __builtin_amdgcn_mfma_f32_16x16x32_bf16(af, bhi, acc[tt], 0, 0, 0);
                acc[tt] = __builtin_amdgcn_mfma_f32_16x16x32_bf16(af, blo, acc[tt], 0, 0, 0);
            }
        }
    }

    // store: C/D row = quad*4+r, col = l15 (<10 kept)
#pragma unroll
    for (int tt = 0; tt < 4; ++tt)
#pragma unroll
        for (int r = 0; r < 4; ++r) {
            int m = (tbase + tt) * 16 + quad * 4 + r;
            if (l15 < CC) I[(size_t)m * CC + l15] = acc[tt][r];
        }
}

// -------------------------------------------- chunked leaky-integrator scan --
__global__ __launch_bounds__(192) void k_integ1(const float* __restrict__ I,
                                                float* __restrict__ out,
                                                float* __restrict__ vend) {
    int b = blockIdx.x;
    int tid = threadIdx.x;
    if (tid >= 160) return;
    int chunk = tid / 10, c = tid % 10;
    int t0 = chunk * 64;
    const float* Ib = I + ((size_t)b * TT + t0) * CC + c;
    float* ob = out + ((size_t)b * TT + t0) * CC + c;
    float v = 0.f;
    for (int g0 = 0; g0 < 64; g0 += 8) {
        float xs[8];
#pragma unroll
        for (int g = 0; g < 8; ++g) xs[g] = Ib[(g0 + g) * CC];
#pragma unroll
        for (int g = 0; g < 8; ++g) {
            v = 0.9f * v + xs[g];
            ob[(g0 + g) * CC] = v;
        }
    }
    vend[((size_t)b * 16 + chunk) * CC + c] = v;
}

__global__ __launch_bounds__(256) void k_integ2(const float* __restrict__ vend,
                                                float* __restrict__ carry) {
    int id = blockIdx.x * 256 + threadIdx.x;
    if (id >= BB * CC) return;
    int b = id / CC, c = id % CC;
    float d64 = 1.f;
#pragma unroll
    for (int i = 0; i < 64; ++i) d64 *= 0.9f;
    float cv = 0.f;
    for (int k = 0; k < 16; ++k) {
        carry[((size_t)b * 16 + k) * CC + c] = cv;
        cv = vend[((size_t)b * 16 + k) * CC + c] + d64 * cv;
    }
}

__global__ __launch_bounds__(256) void k_integ3(const float* __restrict__ carry,
                                                float* __restrict__ out) {
    __shared__ float dec[64];
    if (threadIdx.x == 0) {
        float d = 1.f;
        for (int i = 0; i < 64; ++i) { d *= 0.9f; dec[i] = d; }
    }
    __syncthreads();
    size_t id = (size_t)blockIdx.x * 256 + threadIdx.x;   // B*T*C exactly
    int c = (int)(id % CC);
    size_t bt = id / CC;
    int t = (int)(bt % TT);
    int b = (int)(bt / TT);
    int chunk = t >> 6, tl = t & 63;
    out[id] += dec[tl] * carry[((size_t)b * 16 + chunk) * CC + c];
}

// -----------------------------------------------------------------------------
extern "C" void kernel_launch(void* const* d_in, const int* in_sizes, int n_in,
                              void* d_out, int out_size, void* d_ws, size_t ws_size,
                              hipStream_t stream) {
    const float* x  = (const float*)d_in[0];
    const float* Wh = (const float*)d_in[1];
    const float* Wo = (const float*)d_in[2];

    char* p = (char*)d_ws;
    u64* me = (u64*)p;                        p += (size_t)BB * TT * 4 * 8;    // 16 MB
    u64* mh = (u64*)p;                        p += (size_t)BB * TT * 16 * 8;   // 64 MB
    unsigned short* Wt = (unsigned short*)p;  p += (size_t)HH * 512 * 2;       // 1 MB
    float* I = (float*)p;                     p += (size_t)BB * TT * CC * 4;   // 20 MB
    unsigned short* Wqo = (unsigned short*)p; p += (size_t)16 * 2048 * 2;      // 64 KB
    // vend/carry overlay the (dead after gemm) Wt region: 2 x 320 KB < 1 MB
    float* vend  = (float*)Wt;
    float* carry = (float*)(Wt + 512 * 512);  // +512 KB into Wt region

    hipLaunchKernelGGL(k_enc, dim3(BB), dim3(128), 0, stream, x, me);
    hipLaunchKernelGGL(k_quant, dim3(2048), dim3(256), 0, stream, Wh, Wt);
    hipLaunchKernelGGL(k_quant_o, dim3(128), dim3(256), 0, stream, Wo, Wqo);
    hipLaunchKernelGGL(k_gemm_scan, dim3(128, 8), dim3(256), 0, stream, me, Wt, mh);
    hipLaunchKernelGGL(k_outcur_mfma, dim3(2048), dim3(256), 0, stream, mh, Wqo, I);
    hipLaunchKernelGGL(k_integ1, dim3(BB), dim3(192), 0, stream, I, (float*)d_out, vend);
    hipLaunchKernelGGL(k_integ2, dim3(20), dim3(256), 0, stream, vend, carry);
    hipLaunchKernelGGL(k_integ3, dim3(20480), dim3(256), 0, stream, carry, (float*)d_out);
}